// Round 1
// baseline (795.455 us; speedup 1.0000x reference)
//
#include <hip/hip_runtime.h>
#include <hip/hip_bf16.h>

// Problem geometry: x [B=2, C=16, T=31, H=256, W=256] fp32
#define TDIM 31
#define TS   65536                 // t stride (H*W)
#define CS   (TDIM * TS)           // c stride = 2,031,616
#define BS   (16 * CS)             // b stride = 32,505,856
#define NTOT (2 * BS)              // 65,011,712 elements
#define NPOS 131072                // B*H*W threads for K1
#define K1_BLOCKS 512              // 512 * 256 = NPOS
#define GAP_INV (1.0f / (31.0f * 65536.0f))

__device__ __forceinline__ float frcp(float v) { return __builtin_amdgcn_rcpf(v); }
__device__ __forceinline__ float fexp2(float v) { return __builtin_amdgcn_exp2f(v); }

// tanh(x) = 1 - 2/(exp(2x)+1); exp(2x) = exp2(x * 2*log2(e))
__device__ __forceinline__ float ftanh(float x) {
    float e = fexp2(x * 2.8853900817779268f);
    return 1.0f - 2.0f * frcp(e + 1.0f);
}
// sigmoid(x) = 1/(1+exp(-x))
__device__ __forceinline__ float fsigm(float x) {
    float e = fexp2(x * -1.4426950408889634f);
    return frcp(1.0f + e);
}

// y[o] = bias[o] + sum_c W[o][c] * xv[c]   (W staged as float4[64] in LDS)
__device__ __forceinline__ void matvec16(const float4* __restrict__ W,
                                         const float* __restrict__ bias,
                                         const float* __restrict__ xv,
                                         float* __restrict__ y) {
#pragma unroll
    for (int o = 0; o < 16; ++o) {
        float acc = bias[o];
#pragma unroll
        for (int q = 0; q < 4; ++q) {
            float4 w = W[o * 4 + q];
            acc = fmaf(w.x, xv[4 * q + 0], acc);
            acc = fmaf(w.y, xv[4 * q + 1], acc);
            acc = fmaf(w.z, xv[4 * q + 2], acc);
            acc = fmaf(w.w, xv[4 * q + 3], acc);
        }
        y[o] = acc;
    }
}

__global__ __launch_bounds__(256) void k1_gates_scan(
    const float* __restrict__ x,
    const float* __restrict__ wf1, const float* __restrict__ bf1,
    const float* __restrict__ wf2, const float* __restrict__ bf2,
    const float* __restrict__ ww1, const float* __restrict__ bw1,
    const float* __restrict__ ww2, const float* __restrict__ bw2,
    float* __restrict__ out, float* __restrict__ partials) {
    __shared__ float4 sW[4][64];   // wf1, wf2, ww1, ww2 as 16x(16 floats) = 64 float4
    __shared__ float  sB[4][16];
    __shared__ float  sred[4][16];

    const int tid = threadIdx.x;
    if (tid < 64) {
        sW[0][tid] = ((const float4*)wf1)[tid];
        sW[1][tid] = ((const float4*)wf2)[tid];
        sW[2][tid] = ((const float4*)ww1)[tid];
        sW[3][tid] = ((const float4*)ww2)[tid];
    } else if (tid < 128) {
        int q = tid - 64;
        if (q < 16)      sB[0][q]      = bf1[q];
        else if (q < 32) sB[1][q - 16] = bf2[q - 16];
        else if (q < 48) sB[2][q - 32] = bw1[q - 32];
        else             sB[3][q - 48] = bw2[q - 48];
    }
    __syncthreads();

    const int g = blockIdx.x * 256 + tid;   // 0 .. 131071
    const int b = g >> 16;                  // uniform per block (256 blocks per b)
    const int p = g & 65535;
    const float* __restrict__ xp = x + (size_t)b * BS + p;
    float* __restrict__ op = out + (size_t)b * BS + p;

    float h[16], s[16];
#pragma unroll
    for (int c = 0; c < 16; ++c) { h[c] = 0.0f; s[c] = 0.0f; }

#pragma unroll 1
    for (int t = 0; t < TDIM; ++t) {
        const float* __restrict__ xt = xp + (size_t)t * TS;
        float* __restrict__ ot = op + (size_t)t * TS;

        float xv[16];
#pragma unroll
        for (int c = 0; c < 16; ++c) xv[c] = xt[(size_t)c * CS];

        float a[16], z[16], f[16];
        // FFN "f" branch: tanh(conv2(tanh(conv1(x))))
        matvec16(sW[0], sB[0], xv, a);
#pragma unroll
        for (int c = 0; c < 16; ++c) a[c] = ftanh(a[c]);
        matvec16(sW[1], sB[1], a, z);
#pragma unroll
        for (int c = 0; c < 16; ++c) z[c] = ftanh(z[c]);
        // FFN "w" branch: sigmoid(conv2(tanh(conv1(x))))
        matvec16(sW[2], sB[2], xv, a);
#pragma unroll
        for (int c = 0; c < 16; ++c) a[c] = ftanh(a[c]);
        matvec16(sW[3], sB[3], a, f);
#pragma unroll
        for (int c = 0; c < 16; ++c) f[c] = fsigm(f[c]);

#pragma unroll
        for (int c = 0; c < 16; ++c) {
            // h = f*h + (1-f)*z  ==  f*(h-z) + z
            h[c] = fmaf(f[c], h[c] - z[c], z[c]);
            s[c] += h[c];
            ot[(size_t)c * CS] = h[c];
        }
    }

    // deterministic reduction: wave shuffle -> LDS -> per-block partial
#pragma unroll
    for (int c = 0; c < 16; ++c) {
        float v = s[c];
#pragma unroll
        for (int off = 32; off > 0; off >>= 1) v += __shfl_down(v, off, 64);
        s[c] = v;
    }
    const int lane = tid & 63, wv = tid >> 6;
    if (lane == 0) {
#pragma unroll
        for (int c = 0; c < 16; ++c) sred[wv][c] = s[c];
    }
    __syncthreads();
    if (tid < 16)
        partials[blockIdx.x * 16 + tid] =
            sred[0][tid] + sred[1][tid] + sred[2][tid] + sred[3][tid];
}

__global__ void k2_attention(const float* __restrict__ partials,
                             const float* __restrict__ wsca,
                             const float* __restrict__ bsca,
                             float* __restrict__ att) {
    __shared__ float gap[2][16];
    const int tid = threadIdx.x;
    if (tid < 32) {
        const int b = tid >> 4, c = tid & 15;
        float sum = 0.0f;
        for (int blk = b * 256; blk < (b + 1) * 256; ++blk) sum += partials[blk * 16 + c];
        gap[b][c] = sum * GAP_INV;
    }
    __syncthreads();
    if (tid < 32) {
        const int b = tid >> 4, o = tid & 15;
        float acc = bsca[o];
#pragma unroll
        for (int c = 0; c < 16; ++c) acc = fmaf(wsca[o * 16 + c], gap[b][c], acc);
        att[b * 16 + o] = fsigm(acc);
    }
}

__global__ __launch_bounds__(256) void k3_scale(float* __restrict__ out,
                                                const float* __restrict__ att) {
    __shared__ float sA[32];
    if (threadIdx.x < 32) sA[threadIdx.x] = att[threadIdx.x];
    __syncthreads();
    const int NV4 = NTOT / 4;       // 16,252,928 float4
    const int CSV = CS / 4;         // 507,904 -> i4/CSV == b*16+c exactly
    float4* __restrict__ o4 = (float4*)out;
    for (int i = blockIdx.x * 256 + threadIdx.x; i < NV4; i += gridDim.x * 256) {
        const int bc = i / CSV;
        const float a = sA[bc];
        float4 v = o4[i];
        v.x *= a; v.y *= a; v.z *= a; v.w *= a;
        o4[i] = v;
    }
}

extern "C" void kernel_launch(void* const* d_in, const int* in_sizes, int n_in,
                              void* d_out, int out_size, void* d_ws, size_t ws_size,
                              hipStream_t stream) {
    const float* x    = (const float*)d_in[0];
    const float* wf1  = (const float*)d_in[1];
    const float* bf1  = (const float*)d_in[2];
    const float* wf2  = (const float*)d_in[3];
    const float* bf2  = (const float*)d_in[4];
    const float* ww1  = (const float*)d_in[5];
    const float* bw1  = (const float*)d_in[6];
    const float* ww2  = (const float*)d_in[7];
    const float* bw2  = (const float*)d_in[8];
    const float* wsca = (const float*)d_in[9];
    const float* bsca = (const float*)d_in[10];
    float* out = (float*)d_out;

    float* partials = (float*)d_ws;            // K1_BLOCKS*16 = 8192 floats
    float* att      = partials + K1_BLOCKS * 16;  // 32 floats

    k1_gates_scan<<<K1_BLOCKS, 256, 0, stream>>>(x, wf1, bf1, wf2, bf2,
                                                 ww1, bw1, ww2, bw2, out, partials);
    k2_attention<<<1, 64, 0, stream>>>(partials, wsca, bsca, att);
    k3_scale<<<2048, 256, 0, stream>>>(out, att);
}